// Round 7
// baseline (443.414 us; speedup 1.0000x reference)
//
#include <hip/hip_runtime.h>

#define NN 50000
#define NE 800000
#define NG 2048
#define F 64

constexpr int SCAN_B = 256;
constexpr int NB = (NN + SCAN_B - 1) / SCAN_B;  // 196 blocks

typedef float f4 __attribute__((ext_vector_type(4)));

// ---------------- degree (edge-only in-degree) ----------------
__global__ void deg_kernel(const int* __restrict__ dst, int* __restrict__ deg) {
    int e = blockIdx.x * 256 + threadIdx.x;
    if (e < NE) atomicAdd(&deg[dst[e]], 1);
}

// dinv[v] = rsqrt(deg_edges[v] + 1)   (+1 = self loop)
__global__ void dinv_kernel(const int* __restrict__ deg, float* __restrict__ dinv) {
    int v = blockIdx.x * 256 + threadIdx.x;
    if (v < NN) dinv[v] = rsqrtf((float)(deg[v] + 1));
}

// xd[v] = dinv[v] * x[v]   (32 feats as 8 float4 per row)
__global__ void scalex_kernel(const float4* __restrict__ x4, const float* __restrict__ dinv,
                              float4* __restrict__ xd4) {
    int i = blockIdx.x * 256 + threadIdx.x;
    if (i < NN * 8) {
        int v = i >> 3;
        float d = dinv[v];
        float4 a = x4[i];
        a.x *= d; a.y *= d; a.z *= d; a.w *= d;
        xd4[i] = a;
    }
}

// ---------------- 3-kernel exclusive scan of deg -> rowptr ----------------
__global__ void scan1_kernel(const int* __restrict__ deg, int* __restrict__ bsums) {
    __shared__ int s[256];
    int t = threadIdx.x, i = blockIdx.x * 256 + t;
    s[t] = (i < NN) ? deg[i] : 0;
    __syncthreads();
    for (int off = 128; off > 0; off >>= 1) {
        if (t < off) s[t] += s[t + off];
        __syncthreads();
    }
    if (t == 0) bsums[blockIdx.x] = s[0];
}

__global__ void scan2_kernel(int* __restrict__ bsums, int* __restrict__ rowptr) {
    __shared__ int s[256];
    int t = threadIdx.x;
    int v = (t < NB) ? bsums[t] : 0;
    s[t] = v;
    __syncthreads();
    for (int off = 1; off < 256; off <<= 1) {
        int x = (t >= off) ? s[t - off] : 0;
        __syncthreads();
        s[t] += x;
        __syncthreads();
    }
    if (t < NB) bsums[t] = s[t] - v;   // exclusive block offset
    if (t == 0) rowptr[NN] = NE;
}

__global__ void scan3_kernel(const int* __restrict__ deg, const int* __restrict__ bsums,
                             int* __restrict__ rowptr, int* __restrict__ cursor) {
    __shared__ int s[256];
    int t = threadIdx.x, i = blockIdx.x * 256 + t;
    int v = (i < NN) ? deg[i] : 0;
    s[t] = v;
    __syncthreads();
    for (int off = 1; off < 256; off <<= 1) {
        int x = (t >= off) ? s[t - off] : 0;
        __syncthreads();
        s[t] += x;
        __syncthreads();
    }
    if (i < NN) {
        int rp = bsums[blockIdx.x] + s[t] - v;
        rowptr[i] = rp;
        cursor[i] = rp;
    }
}

// scatter edges into CSR slots (order within a row irrelevant)
__global__ void fill_kernel(const int* __restrict__ src, const int* __restrict__ dst,
                            int* __restrict__ cursor, int* __restrict__ col) {
    int e = blockIdx.x * 256 + threadIdx.x;
    if (e < NE) {
        int slot = atomicAdd(&cursor[dst[e]], 1);
        col[slot] = src[e];
    }
}

// ---------------- layer-1 aggregation, feature-HALF per XCD group --------------
// s[v] = dinv[v] * (sum_{u->v} xd[u] + xd[v]);  each block handles 16 of 32 feats.
// Half-plane = 3.2MB, fits one XCD L2.  blocks: 25000; bi&7 -> XCD (round-robin).
__global__ void agg32_kernel(const f4* __restrict__ g4, const int* __restrict__ rowptr,
                             const int* __restrict__ col, const float* __restrict__ dinv,
                             float* __restrict__ out) {
    int tid = threadIdx.x, lane = tid & 63;
    int bi = blockIdx.x;
    int h = (bi & 7) >> 2;                  // XCDs 0-3 -> half 0, XCDs 4-7 -> half 1
    int vg = ((bi >> 3) << 2) | (bi & 3);   // 0..12499, each once per half
    int v = vg * 4 + (tid >> 6);
    int slot = lane >> 2, fj = lane & 3;    // 16 edge slots x 4 f4-lanes (16 feats)
    int beg = rowptr[v], end = rowptr[v + 1];
    f4 acc = {0.f, 0.f, 0.f, 0.f};
    for (int base = beg; base < end; base += 32) {
        f4 a[2];
        float w[2];
#pragma unroll
        for (int j = 0; j < 2; ++j) {
            int e = base + slot + j * 16;
            int ce = (e < end) ? e : (end - 1);
            w[j] = (e < end) ? 1.f : 0.f;
            int u = col[ce];
            a[j] = g4[(long)u * 8 + h * 4 + fj];   // 64B from L2-resident half-plane
        }
        acc += w[0] * a[0] + w[1] * a[1];
    }
    // reduce across 16 slots (lane bits 2..5)
#pragma unroll
    for (int m = 4; m < 64; m <<= 1) {
        acc.x += __shfl_xor(acc.x, m);
        acc.y += __shfl_xor(acc.y, m);
        acc.z += __shfl_xor(acc.z, m);
        acc.w += __shfl_xor(acc.w, m);
    }
    f4 self = g4[(long)v * 8 + h * 4 + fj];
    float d = dinv[v];
    acc = d * (acc + self);
    if (slot < 4) {   // lanes 0-15 write 16 distinct scalars = one 64B line
        float comp = (slot == 0) ? acc.x : (slot == 1) ? acc.y : (slot == 2) ? acc.z : acc.w;
        out[(long)v * 32 + h * 16 + fj * 4 + slot] = comp;
    }
}

// ---------------- aggregation, feature-QUARTER per XCD pair ---------------------
// h[v] = relu(dinv[v]*(sum g[u] + g[v]) + b);  each block handles 16 of 64 feats.
// Quarter-plane = 3.2MB, fits one XCD L2.  blocks: 50000; bi&7 -> XCD.
template <bool POOL>
__global__ void agg4_kernel(const f4* __restrict__ g4, const int* __restrict__ rowptr,
                            const int* __restrict__ col, const float* __restrict__ dinv,
                            const f4* __restrict__ bias4, float* __restrict__ out,
                            const int* __restrict__ batch, float* __restrict__ pooled,
                            float* __restrict__ counts) {
    int tid = threadIdx.x, lane = tid & 63;
    int bi = blockIdx.x;
    int q = (bi & 7) >> 1;                  // quarter 0..3 pinned to XCD pair
    int vg = ((bi >> 3) << 1) | (bi & 1);   // 0..12499, each once per quarter
    int v = vg * 4 + (tid >> 6);
    int slot = lane >> 2, fj = lane & 3;    // 16 edge slots x 4 f4-lanes (16 feats)
    int beg = rowptr[v], end = rowptr[v + 1];
    f4 acc = {0.f, 0.f, 0.f, 0.f};
    for (int base = beg; base < end; base += 32) {
        f4 a[2];
        float w[2];
#pragma unroll
        for (int j = 0; j < 2; ++j) {
            int e = base + slot + j * 16;
            int ce = (e < end) ? e : (end - 1);
            w[j] = (e < end) ? 1.f : 0.f;
            int u = col[ce];
            a[j] = g4[(long)u * 16 + q * 4 + fj];  // 64B from L2-resident quarter-plane
        }
        acc += w[0] * a[0] + w[1] * a[1];
    }
    // reduce across 16 slots (lane bits 2..5)
#pragma unroll
    for (int m = 4; m < 64; m <<= 1) {
        acc.x += __shfl_xor(acc.x, m);
        acc.y += __shfl_xor(acc.y, m);
        acc.z += __shfl_xor(acc.z, m);
        acc.w += __shfl_xor(acc.w, m);
    }
    f4 self = g4[(long)v * 16 + q * 4 + fj];
    float d = dinv[v];
    f4 bb = bias4[q * 4 + fj];
    f4 hv;
    hv.x = fmaxf(fmaf(d, acc.x + self.x, bb.x), 0.f);
    hv.y = fmaxf(fmaf(d, acc.y + self.y, bb.y), 0.f);
    hv.z = fmaxf(fmaf(d, acc.z + self.z, bb.z), 0.f);
    hv.w = fmaxf(fmaf(d, acc.w + self.w, bb.w), 0.f);
    if (slot < 4) {   // lanes 0-15: 16 distinct feature scalars = one 64B line
        float comp = (slot == 0) ? hv.x : (slot == 1) ? hv.y : (slot == 2) ? hv.z : hv.w;
        int feat = q * 16 + fj * 4 + slot;
        if (POOL) {
            atomicAdd(&pooled[(long)batch[v] * F + feat], comp);
        } else {
            out[(long)v * F + feat] = comp;
        }
    }
    if (POOL && q == 0 && lane == 0) atomicAdd(&counts[batch[v]], 1.0f);
}

// ---------------- GEMM: 16 nodes/block, 256 threads -------------------------------
// RELU_BIAS: out = relu(in@W + b)          (layer-1 path, K=32)
// else:      out = dinv[n] * (in@W)        (pre-aggregation scaling, K=64)
template <int K, bool RELU_BIAS>
__global__ void gemm_kernel(const float* __restrict__ in, const float* __restrict__ W,
                            const float* __restrict__ bias, const float* __restrict__ dinv,
                            float* __restrict__ out) {
    __shared__ float Ws[K * F];
    int t = threadIdx.x;
#pragma unroll
    for (int i = 0; i < K * F / 256; ++i) Ws[i * 256 + t] = W[i * 256 + t];
    __syncthreads();
    int f = t & 63;
    int slot = __builtin_amdgcn_readfirstlane(t >> 6);  // wave-uniform
    int n0 = blockIdx.x * 16 + slot;                    // nodes n0, n0+4, n0+8, n0+12
    float acc0 = 0.f, acc1 = 0.f, acc2 = 0.f, acc3 = 0.f;
    const float* r0 = in + (long)n0 * K;
    const float* r1 = r0 + 4 * K;
    const float* r2 = r0 + 8 * K;
    const float* r3 = r0 + 12 * K;
#pragma unroll
    for (int k = 0; k < K; ++k) {
        float w = Ws[k * F + f];
        acc0 = fmaf(r0[k], w, acc0);
        acc1 = fmaf(r1[k], w, acc1);
        acc2 = fmaf(r2[k], w, acc2);
        acc3 = fmaf(r3[k], w, acc3);
    }
    if (RELU_BIAS) {
        float b = bias[f];
        out[(long)n0 * F + f]        = fmaxf(acc0 + b, 0.f);
        out[(long)(n0 + 4) * F + f]  = fmaxf(acc1 + b, 0.f);
        out[(long)(n0 + 8) * F + f]  = fmaxf(acc2 + b, 0.f);
        out[(long)(n0 + 12) * F + f] = fmaxf(acc3 + b, 0.f);
    } else {
        out[(long)n0 * F + f]        = dinv[n0] * acc0;
        out[(long)(n0 + 4) * F + f]  = dinv[n0 + 4] * acc1;
        out[(long)(n0 + 8) * F + f]  = dinv[n0 + 8] * acc2;
        out[(long)(n0 + 12) * F + f] = dinv[n0 + 12] * acc3;
    }
}

// ---------------- head: out = relu(pooled/cnt @ lw1 + lb1) @ lw2 + lb2 ----------------
__global__ void head_kernel(const float* __restrict__ pooled, const float* __restrict__ counts,
                            const float* __restrict__ lw1, const float* __restrict__ lb1,
                            const float* __restrict__ lw2, const float* __restrict__ lb2,
                            float* __restrict__ out) {
    __shared__ float p[F];
    __shared__ float hid[F];
    int gid = blockIdx.x, t = threadIdx.x;
    float cnt = fmaxf(counts[gid], 1.0f);
    p[t] = pooled[(long)gid * F + t] / cnt;
    __syncthreads();
    float acc = lb1[t];
#pragma unroll 8
    for (int k = 0; k < F; ++k) acc = fmaf(p[k], lw1[k * F + t], acc);
    hid[t] = fmaxf(acc, 0.f);
    __syncthreads();
    if (t < 2) {
        float a = lb2[t];
#pragma unroll 8
        for (int k = 0; k < F; ++k) a = fmaf(hid[k], lw2[k * 2 + t], a);
        out[(long)gid * 2 + t] = a;
    }
}

extern "C" void kernel_launch(void* const* d_in, const int* in_sizes, int n_in,
                              void* d_out, int out_size, void* d_ws, size_t ws_size,
                              hipStream_t stream) {
    const float* x    = (const float*)d_in[0];
    const int*   ei   = (const int*)d_in[1];   // [2, NE]: src then dst
    const int*   bat  = (const int*)d_in[2];
    const float* W1   = (const float*)d_in[3];
    const float* b1   = (const float*)d_in[4];
    const float* W2   = (const float*)d_in[5];
    const float* b2   = (const float*)d_in[6];
    const float* W3   = (const float*)d_in[7];
    const float* b3   = (const float*)d_in[8];
    const float* lw1  = (const float*)d_in[9];
    const float* lb1  = (const float*)d_in[10];
    const float* lw2  = (const float*)d_in[11];
    const float* lb2  = (const float*)d_in[12];
    float* out = (float*)d_out;

    const int* src = ei;
    const int* dst = ei + NE;

    // workspace carve-up (256B aligned)
    char* ws = (char*)d_ws;
    size_t off = 0;
    auto carve = [&](size_t bytes) {
        void* p = ws + off;
        off += (bytes + 255) & ~(size_t)255;
        return p;
    };
    int*   deg     = (int*)carve(NN * 4);
    float* dinv    = (float*)carve(NN * 4);
    int*   rowptr  = (int*)carve((NN + 1) * 4);
    int*   cursor  = (int*)carve(NN * 4);
    int*   bsums   = (int*)carve(256 * 4);
    int*   col     = (int*)carve((size_t)NE * 4);
    float* xd      = (float*)carve((size_t)NN * 32 * 4);
    float* sbuf    = (float*)carve((size_t)NN * 32 * 4);
    float* bufA    = (float*)carve((size_t)NN * F * 4);
    float* bufB    = (float*)carve((size_t)NN * F * 4);
    float* pooled  = (float*)carve((size_t)NG * F * 4 + NG * 4);
    float* counts  = pooled + (size_t)NG * F;

    hipMemsetAsync(deg, 0, NN * 4, stream);
    hipMemsetAsync(pooled, 0, ((size_t)NG * F + NG) * 4, stream);

    deg_kernel<<<(NE + 255) / 256, 256, 0, stream>>>(dst, deg);
    dinv_kernel<<<NB, 256, 0, stream>>>(deg, dinv);
    scalex_kernel<<<(NN * 8 + 255) / 256, 256, 0, stream>>>((const float4*)x, dinv, (float4*)xd);
    scan1_kernel<<<NB, 256, 0, stream>>>(deg, bsums);
    scan2_kernel<<<1, 256, 0, stream>>>(bsums, rowptr);
    scan3_kernel<<<NB, 256, 0, stream>>>(deg, bsums, rowptr, cursor);
    fill_kernel<<<(NE + 255) / 256, 256, 0, stream>>>(src, dst, cursor, col);

    const int gridH = 2 * (NN / 4);    // 25000 blocks: feature-half x 4 nodes
    const int gridQ = 4 * (NN / 4);    // 50000 blocks: feature-quarter x 4 nodes
    const int gridG = NN / 16;         // 3125 blocks for gemm

    // layer 1: aggregate raw 32-feat xd (half-split), then GEMM with fused bias+relu
    agg32_kernel<<<gridH, 256, 0, stream>>>((const f4*)xd, rowptr, col, dinv, sbuf);
    gemm_kernel<32, true><<<gridG, 256, 0, stream>>>(sbuf, W1, b1, dinv, bufA);

    // layer 2: g = dinv*(h1@W2), aggregate (quarter-split) with bias+relu
    gemm_kernel<64, false><<<gridG, 256, 0, stream>>>(bufA, W2, nullptr, dinv, bufB);
    agg4_kernel<false><<<gridQ, 256, 0, stream>>>((const f4*)bufB, rowptr, col, dinv,
                                                  (const f4*)b2, bufA,
                                                  nullptr, nullptr, nullptr);
    // layer 3: fused mean-pool accumulation
    gemm_kernel<64, false><<<gridG, 256, 0, stream>>>(bufA, W3, nullptr, dinv, bufB);
    agg4_kernel<true><<<gridQ, 256, 0, stream>>>((const f4*)bufB, rowptr, col, dinv,
                                                 (const f4*)b3, nullptr,
                                                 bat, pooled, counts);
    // head MLP
    head_kernel<<<NG, 64, 0, stream>>>(pooled, counts, lw1, lb1, lw2, lb2, out);
}